// Round 1
// baseline (209.335 us; speedup 1.0000x reference)
//
#include <hip/hip_runtime.h>
#include <hip/hip_bf16.h>
#include <stdint.h>

// Problem dims (fixed by reference): x[4096][1024] fp32, W[32][1024][1024] fp32,
// b[32][1024] fp32, ids[8] int, weights[8] fp32; out[4096][1024] fp32.
// Math: Wc = sum_k w_k * W[ids_k]  (1024x1024); out = x @ Wc^T + bc.

typedef __attribute__((ext_vector_type(8))) short short8;
typedef __attribute__((ext_vector_type(4))) float float4v;

#define DIMK 1024
#define DIMN 1024
#define DIMM 4096

__device__ __forceinline__ unsigned short f2bf_rtn(float f) {
  union { float f; unsigned u; } v; v.f = f;
  unsigned u = v.u;
  return (unsigned short)((u + 0x7fffu + ((u >> 16) & 1u)) >> 16);
}

// blocks [0,1024): build Wc (bf16) + bc; blocks [1024,5120): convert x -> bf16
__global__ __launch_bounds__(256) void prep_kernel(
    const float* __restrict__ x, const float* __restrict__ W,
    const float* __restrict__ bia, const int* __restrict__ ids,
    const float* __restrict__ wts,
    unsigned short* __restrict__ xb, unsigned short* __restrict__ Wc,
    float* __restrict__ bc, int K)
{
  const int bid = blockIdx.x;
  if (bid < 1024) {
    const int t  = bid * 256 + threadIdx.x;   // 0..262143 (float4 groups of Wc)
    const int o  = t >> 8;                    // 256 groups per output row
    const int d4 = (t & 255) << 2;
    float ax = 0.f, ay = 0.f, az = 0.f, aw = 0.f;
    for (int k = 0; k < K; ++k) {
      const float wk = wts[k];
      const float4 w4 = *reinterpret_cast<const float4*>(
          &W[((size_t)ids[k] << 20) + ((size_t)o << 10) + d4]);
      ax += wk * w4.x; ay += wk * w4.y; az += wk * w4.z; aw += wk * w4.w;
    }
    ushort4 r;
    r.x = f2bf_rtn(ax); r.y = f2bf_rtn(ay); r.z = f2bf_rtn(az); r.w = f2bf_rtn(aw);
    *reinterpret_cast<ushort4*>(&Wc[(size_t)t << 2]) = r;
    if (t < DIMN) {
      float s = 0.f;
      for (int k = 0; k < K; ++k) s += wts[k] * bia[ids[k] * DIMN + t];
      bc[t] = s;
    }
  } else {
    const size_t t = (size_t)(bid - 1024) * 256 + threadIdx.x;  // 1M float4 groups
    const float4 v = *reinterpret_cast<const float4*>(&x[t << 2]);
    ushort4 r;
    r.x = f2bf_rtn(v.x); r.y = f2bf_rtn(v.y); r.z = f2bf_rtn(v.z); r.w = f2bf_rtn(v.w);
    *reinterpret_cast<ushort4*>(&xb[t << 2]) = r;
  }
}

__device__ __forceinline__ void load_lds16(const void* g, void* l) {
  __builtin_amdgcn_global_load_lds(
      (const __attribute__((address_space(1))) void*)g,
      (__attribute__((address_space(3))) void*)l, 16, 0, 0);
}

// 128x128 block tile, BK=32, 4 waves each computing a 64x64 subtile as
// 4x4 MFMA 16x16x32 bf16 tiles. Both A (x) and B (Wc) are row-major with K
// contiguous (B^T-style GEMM). Verified fragment layouts (learn_hip m89/m91/m120):
//   A/B operand: idx16 = lane&15, k = (lane>>4)*8 + j
//   C/D:         col   = lane&15, row = (lane>>4)*4 + reg
__global__ __launch_bounds__(256) void gemm_kernel(
    const unsigned short* __restrict__ xb,   // [4096][1024] bf16
    const unsigned short* __restrict__ Wc,   // [1024][1024] bf16 (row=n, col=k)
    const float* __restrict__ bc,            // [1024]
    float* __restrict__ out)                 // [4096][1024] fp32
{
  constexpr int BK = 32;
  __shared__ __align__(16) unsigned short As[128 * BK];
  __shared__ __align__(16) unsigned short Bs[128 * BK];

  const int tid  = threadIdx.x;
  const int wave = tid >> 6;
  const int lane = tid & 63;
  const int m0 = blockIdx.y * 128;
  const int n0 = blockIdx.x * 128;

  // Staging: tile = 8 chunks of (16 rows x 32 cols); wave w owns chunks 2w,2w+1.
  // global_load_lds writes lane l at ldsbase + l*16B == row l/4, col (l%4)*8 — matches.
  const int crow = lane >> 2;
  const int ccol = (lane & 3) << 3;
  const int cid0 = wave * 2;
  const unsigned short* gA0 = xb + (size_t)(m0 + cid0 * 16 + crow) * DIMK + ccol;
  const unsigned short* gA1 = gA0 + 16 * DIMK;
  const unsigned short* gB0 = Wc + (size_t)(n0 + cid0 * 16 + crow) * DIMK + ccol;
  const unsigned short* gB1 = gB0 + 16 * DIMK;
  unsigned short* lA0 = &As[cid0 * 512];
  unsigned short* lA1 = &As[cid0 * 512 + 512];
  unsigned short* lB0 = &Bs[cid0 * 512];
  unsigned short* lB1 = &Bs[cid0 * 512 + 512];

  const int wm0  = (wave >> 1) * 64;
  const int wn0  = (wave & 1) * 64;
  const int quad = lane >> 4;
  const int r16  = lane & 15;

  const float4v zero = {0.f, 0.f, 0.f, 0.f};
  float4v acc[4][4];
#pragma unroll
  for (int i = 0; i < 4; ++i)
#pragma unroll
    for (int j = 0; j < 4; ++j) acc[i][j] = zero;

  for (int k0 = 0; k0 < DIMK; k0 += BK) {
    load_lds16(gA0 + k0, lA0);
    load_lds16(gA1 + k0, lA1);
    load_lds16(gB0 + k0, lB0);
    load_lds16(gB1 + k0, lB1);
    __syncthreads();   // drains vmcnt (incl. global_load_lds) before reads

    short8 af[4], bf[4];
#pragma unroll
    for (int mt = 0; mt < 4; ++mt)
      af[mt] = *reinterpret_cast<const short8*>(&As[(wm0 + mt * 16 + r16) * BK + quad * 8]);
#pragma unroll
    for (int nt = 0; nt < 4; ++nt)
      bf[nt] = *reinterpret_cast<const short8*>(&Bs[(wn0 + nt * 16 + r16) * BK + quad * 8]);

#pragma unroll
    for (int mt = 0; mt < 4; ++mt)
#pragma unroll
      for (int nt = 0; nt < 4; ++nt)
        acc[mt][nt] = __builtin_amdgcn_mfma_f32_16x16x32_bf16(af[mt], bf[nt], acc[mt][nt], 0, 0, 0);

    __syncthreads();   // all reads done before next-iter overwrite
  }

#pragma unroll
  for (int nt = 0; nt < 4; ++nt) {
    const int col = n0 + wn0 + nt * 16 + r16;
    const float bias = bc[col];
#pragma unroll
    for (int mt = 0; mt < 4; ++mt) {
      const int rbase = m0 + wm0 + mt * 16 + quad * 4;
#pragma unroll
      for (int r = 0; r < 4; ++r)
        out[(size_t)(rbase + r) * DIMN + col] = acc[mt][nt][r] + bias;
    }
  }
}

extern "C" void kernel_launch(void* const* d_in, const int* in_sizes, int n_in,
                              void* d_out, int out_size, void* d_ws, size_t ws_size,
                              hipStream_t stream) {
  const float* x   = (const float*)d_in[0];
  const float* W   = (const float*)d_in[1];
  const float* b   = (const float*)d_in[2];
  const int*   ids = (const int*)d_in[3];
  const float* wts = (const float*)d_in[4];
  float* out = (float*)d_out;
  const int K = in_sizes[3];

  // workspace layout: xb 8 MB | Wc 2 MB | bc 4 KB
  unsigned short* xb = (unsigned short*)d_ws;
  unsigned short* Wc = (unsigned short*)((char*)d_ws + (8u << 20));
  float*          bc = (float*)((char*)d_ws + (10u << 20));

  prep_kernel<<<5120, 256, 0, stream>>>(x, W, b, ids, wts, xb, Wc, bc, K);
  dim3 grid(DIMN / 128, DIMM / 128);  // 8 x 32 = 256 blocks
  gemm_kernel<<<grid, 256, 0, stream>>>(xb, Wc, bc, out);
}

// Round 2
// 201.925 us; speedup vs baseline: 1.0367x; 1.0367x over previous
//
#include <hip/hip_runtime.h>
#include <hip/hip_bf16.h>
#include <stdint.h>

// out = x @ Wc^T + bc, where Wc = sum_k w_k * W[ids_k] (1024x1024), x:[4096][1024].
// prep: build Wc (bf16) + bc, convert x -> bf16.
// gemm: 64x128 tile, BK=64, 512 blocks (2/CU), XOR-swizzled LDS, MFMA 16x16x32 bf16.

typedef __attribute__((ext_vector_type(8))) short short8;
typedef __attribute__((ext_vector_type(4))) float float4v;

#define DIMK 1024
#define DIMN 1024
#define DIMM 4096

__device__ __forceinline__ unsigned short f2bf_rtn(float f) {
  union { float f; unsigned u; } v; v.f = f;
  unsigned u = v.u;
  return (unsigned short)((u + 0x7fffu + ((u >> 16) & 1u)) >> 16);
}

// blocks [0,1024): build Wc (bf16) + bc; blocks [1024,5120): convert x -> bf16
__global__ __launch_bounds__(256) void prep_kernel(
    const float* __restrict__ x, const float* __restrict__ W,
    const float* __restrict__ bia, const int* __restrict__ ids,
    const float* __restrict__ wts,
    unsigned short* __restrict__ xb, unsigned short* __restrict__ Wc,
    float* __restrict__ bc, int K)
{
  const int bid = blockIdx.x;
  if (bid < 1024) {
    const int t  = bid * 256 + threadIdx.x;   // float4 groups of Wc
    const int o  = t >> 8;
    const int d4 = (t & 255) << 2;
    float ax = 0.f, ay = 0.f, az = 0.f, aw = 0.f;
    for (int k = 0; k < K; ++k) {
      const float wk = wts[k];
      const float4 w4 = *reinterpret_cast<const float4*>(
          &W[((size_t)ids[k] << 20) + ((size_t)o << 10) + d4]);
      ax += wk * w4.x; ay += wk * w4.y; az += wk * w4.z; aw += wk * w4.w;
    }
    ushort4 r;
    r.x = f2bf_rtn(ax); r.y = f2bf_rtn(ay); r.z = f2bf_rtn(az); r.w = f2bf_rtn(aw);
    *reinterpret_cast<ushort4*>(&Wc[(size_t)t << 2]) = r;
    if (t < DIMN) {
      float s = 0.f;
      for (int k = 0; k < K; ++k) s += wts[k] * bia[ids[k] * DIMN + t];
      bc[t] = s;
    }
  } else {
    const size_t t = (size_t)(bid - 1024) * 256 + threadIdx.x;
    const float4 v = *reinterpret_cast<const float4*>(&x[t << 2]);
    ushort4 r;
    r.x = f2bf_rtn(v.x); r.y = f2bf_rtn(v.y); r.z = f2bf_rtn(v.z); r.w = f2bf_rtn(v.w);
    *reinterpret_cast<ushort4*>(&xb[t << 2]) = r;
  }
}

__device__ __forceinline__ void load_lds16(const void* g, void* l) {
  __builtin_amdgcn_global_load_lds(
      (const __attribute__((address_space(1))) void*)g,
      (__attribute__((address_space(3))) void*)l, 16, 0, 0);
}

// Tile 64(M) x 128(N), BK=64. 4 waves, wave computes 32x64 (2x4 MFMA 16x16x32).
// LDS layout XOR-swizzled: row r, global 16B-group g stored at phys group g^(r&7).
// Staging chunk = 8 rows x 64 cols (1 KB): lane l -> row l>>3, phys group l&7,
// so lane's GLOBAL source column group = (l&7)^(l>>3)  (since row&7 == l>>3).
// ds_read: group g=s*4+quad at row r -> phys (s*4+quad)^(r16&7): conflict-free
// (enumerated: 8 distinct 4-bank groups x 2 lanes = 32 banks, 2-way = free).
__global__ __launch_bounds__(256, 2) void gemm_kernel(
    const unsigned short* __restrict__ xb,   // [4096][1024] bf16
    const unsigned short* __restrict__ Wc,   // [1024][1024] bf16 (row=n)
    const float* __restrict__ bc,            // [1024]
    float* __restrict__ out)                 // [4096][1024] fp32
{
  constexpr int BK = 64;
  __shared__ __align__(16) unsigned short As[64 * BK];    // 8 KB
  __shared__ __align__(16) unsigned short Bs[128 * BK];   // 16 KB

  const int tid  = threadIdx.x;
  const int wave = tid >> 6;
  const int lane = tid & 63;
  const int m0 = blockIdx.y * 64;
  const int n0 = blockIdx.x * 128;

  // staging: wave handles A rows [wave*16, +16) as 2 chunks, B rows [wave*32, +32) as 4.
  const int srow = lane >> 3;
  const int scol = (((lane & 7) ^ srow) << 3);
  const unsigned short* gA0 = xb + (size_t)(m0 + wave * 16 + srow) * DIMK + scol;
  const unsigned short* gA1 = gA0 + 8 * DIMK;
  const unsigned short* gB0 = Wc + (size_t)(n0 + wave * 32 + srow) * DIMK + scol;
  const unsigned short* gB1 = gB0 + 8 * DIMK;
  const unsigned short* gB2 = gB0 + 16 * DIMK;
  const unsigned short* gB3 = gB0 + 24 * DIMK;
  unsigned short* lA0 = &As[wave * 16 * BK];
  unsigned short* lA1 = lA0 + 8 * BK;
  unsigned short* lB0 = &Bs[wave * 32 * BK];
  unsigned short* lB1 = lB0 + 8 * BK;
  unsigned short* lB2 = lB0 + 16 * BK;
  unsigned short* lB3 = lB0 + 24 * BK;

  const int wm   = (wave >> 1) * 32;
  const int wn   = (wave & 1) * 64;
  const int quad = lane >> 4;
  const int r16  = lane & 15;
  const int rx   = r16 & 7;
  const int po0  = ((quad ^ rx) << 3);        // kstep 0 phys group offset (elems)
  const int po1  = (((4 + quad) ^ rx) << 3);  // kstep 1

  const float4v zero = {0.f, 0.f, 0.f, 0.f};
  float4v acc[2][4];
#pragma unroll
  for (int i = 0; i < 2; ++i)
#pragma unroll
    for (int j = 0; j < 4; ++j) acc[i][j] = zero;

  for (int k0 = 0; k0 < DIMK; k0 += BK) {
    load_lds16(gA0 + k0, lA0);
    load_lds16(gA1 + k0, lA1);
    load_lds16(gB0 + k0, lB0);
    load_lds16(gB1 + k0, lB1);
    load_lds16(gB2 + k0, lB2);
    load_lds16(gB3 + k0, lB3);
    __syncthreads();

#pragma unroll
    for (int s = 0; s < 2; ++s) {
      const int po = s ? po1 : po0;
      short8 af[2], bf[4];
#pragma unroll
      for (int mt = 0; mt < 2; ++mt)
        af[mt] = *reinterpret_cast<const short8*>(&As[(wm + mt * 16 + r16) * BK + po]);
#pragma unroll
      for (int nt = 0; nt < 4; ++nt)
        bf[nt] = *reinterpret_cast<const short8*>(&Bs[(wn + nt * 16 + r16) * BK + po]);
#pragma unroll
      for (int mt = 0; mt < 2; ++mt)
#pragma unroll
        for (int nt = 0; nt < 4; ++nt)
          acc[mt][nt] = __builtin_amdgcn_mfma_f32_16x16x32_bf16(af[mt], bf[nt], acc[mt][nt], 0, 0, 0);
    }
    __syncthreads();
  }

#pragma unroll
  for (int nt = 0; nt < 4; ++nt) {
    const int col = n0 + wn + nt * 16 + r16;
    const float bias = bc[col];
#pragma unroll
    for (int mt = 0; mt < 2; ++mt) {
      const int rbase = m0 + wm + mt * 16 + quad * 4;
#pragma unroll
      for (int r = 0; r < 4; ++r)
        out[(size_t)(rbase + r) * DIMN + col] = acc[mt][nt][r] + bias;
    }
  }
}

extern "C" void kernel_launch(void* const* d_in, const int* in_sizes, int n_in,
                              void* d_out, int out_size, void* d_ws, size_t ws_size,
                              hipStream_t stream) {
  const float* x   = (const float*)d_in[0];
  const float* W   = (const float*)d_in[1];
  const float* b   = (const float*)d_in[2];
  const int*   ids = (const int*)d_in[3];
  const float* wts = (const float*)d_in[4];
  float* out = (float*)d_out;
  const int K = in_sizes[3];

  // workspace: xb 8 MB | Wc 2 MB | bc 4 KB
  unsigned short* xb = (unsigned short*)d_ws;
  unsigned short* Wc = (unsigned short*)((char*)d_ws + (8u << 20));
  float*          bc = (float*)((char*)d_ws + (10u << 20));

  prep_kernel<<<5120, 256, 0, stream>>>(x, W, b, ids, wts, xb, Wc, bc, K);
  dim3 grid(DIMN / 128, DIMM / 64);   // 8 x 64 = 512 blocks, 2/CU
  gemm_kernel<<<grid, 256, 0, stream>>>(xb, Wc, bc, out);
}